// Round 1
// baseline (282.140 us; speedup 1.0000x reference)
//
#include <hip/hip_runtime.h>
#include <stdint.h>
#include <string.h>

// ---------------------------------------------------------------------------
// JAX threefry2x32 (20 rounds, 5 groups of 4), exact reproduction of
// jax/_src/prng.py::_threefry2x32. Works on host and device.
// ---------------------------------------------------------------------------
__host__ __device__ inline uint32_t rotl32(uint32_t x, uint32_t r) {
  return (x << r) | (x >> (32u - r));
}

__host__ __device__ inline void threefry2x32(uint32_t k0, uint32_t k1,
                                             uint32_t x0, uint32_t x1,
                                             uint32_t& o0, uint32_t& o1) {
  const uint32_t ks2 = k0 ^ k1 ^ 0x1BD11BDAu;
  x0 += k0; x1 += k1;
  // group 1: rotations [13,15,26,6]
  x0 += x1; x1 = rotl32(x1, 13); x1 ^= x0;
  x0 += x1; x1 = rotl32(x1, 15); x1 ^= x0;
  x0 += x1; x1 = rotl32(x1, 26); x1 ^= x0;
  x0 += x1; x1 = rotl32(x1,  6); x1 ^= x0;
  x0 += k1; x1 += ks2 + 1u;
  // group 2: rotations [17,29,16,24]
  x0 += x1; x1 = rotl32(x1, 17); x1 ^= x0;
  x0 += x1; x1 = rotl32(x1, 29); x1 ^= x0;
  x0 += x1; x1 = rotl32(x1, 16); x1 ^= x0;
  x0 += x1; x1 = rotl32(x1, 24); x1 ^= x0;
  x0 += ks2; x1 += k0 + 2u;
  // group 3
  x0 += x1; x1 = rotl32(x1, 13); x1 ^= x0;
  x0 += x1; x1 = rotl32(x1, 15); x1 ^= x0;
  x0 += x1; x1 = rotl32(x1, 26); x1 ^= x0;
  x0 += x1; x1 = rotl32(x1,  6); x1 ^= x0;
  x0 += k0; x1 += k1 + 3u;
  // group 4
  x0 += x1; x1 = rotl32(x1, 17); x1 ^= x0;
  x0 += x1; x1 = rotl32(x1, 29); x1 ^= x0;
  x0 += x1; x1 = rotl32(x1, 16); x1 ^= x0;
  x0 += x1; x1 = rotl32(x1, 24); x1 ^= x0;
  x0 += k1; x1 += ks2 + 4u;
  // group 5
  x0 += x1; x1 = rotl32(x1, 13); x1 ^= x0;
  x0 += x1; x1 = rotl32(x1, 15); x1 ^= x0;
  x0 += x1; x1 = rotl32(x1, 26); x1 ^= x0;
  x0 += x1; x1 = rotl32(x1,  6); x1 ^= x0;
  o0 = x0 + ks2;
  o1 = x1 + k0 + 5u;
}

// ---------------------------------------------------------------------------
// bits -> uniform(lo=nextafter(-1,0), hi=1) -> sqrt(2)*erfinv(u)
// exactly as jax.random.normal lowers (XLA ErfInv32 = Giles single-prec poly).
// ---------------------------------------------------------------------------
__device__ inline float bits_to_normal(uint32_t bits) {
  const float LO = -0.99999994f;  // nextafterf(-1, 0)
  // uniform [0,1): 23 mantissa bits
  float f = __uint_as_float((bits >> 9) | 0x3f800000u) - 1.0f;
  // span (1 - lo) rounds to exactly 2.0f in fp32; 2*f is exact
  float u = fmaxf(LO, __builtin_fmaf(f, 2.0f, LO));
  float t = u * u;
  float w = -__logf(1.0f - t);  // 1-t exact by Sterbenz when t>=0.5
  float p;
  if (w < 5.0f) {
    float ww = w - 2.5f;
    p = 2.81022636e-08f;
    p = __builtin_fmaf(p, ww, 3.43273939e-07f);
    p = __builtin_fmaf(p, ww, -3.5233877e-06f);
    p = __builtin_fmaf(p, ww, -4.39150654e-06f);
    p = __builtin_fmaf(p, ww, 0.00021858087f);
    p = __builtin_fmaf(p, ww, -0.00125372503f);
    p = __builtin_fmaf(p, ww, -0.00417768164f);
    p = __builtin_fmaf(p, ww, 0.246640727f);
    p = __builtin_fmaf(p, ww, 1.50140941f);
  } else {
    float ww = sqrtf(w) - 3.0f;
    p = -0.000200214257f;
    p = __builtin_fmaf(p, ww, 0.000100950558f);
    p = __builtin_fmaf(p, ww, 0.00134934322f);
    p = __builtin_fmaf(p, ww, -0.00367342844f);
    p = __builtin_fmaf(p, ww, 0.00573950773f);
    p = __builtin_fmaf(p, ww, -0.0076224613f);
    p = __builtin_fmaf(p, ww, 0.00943887047f);
    p = __builtin_fmaf(p, ww, 1.00167406f);
    p = __builtin_fmaf(p, ww, 2.83297682f);
  }
  return 1.41421356f * (p * u);  // float32(sqrt(2)) * erfinv
}

// out[n] = (normal_h[n] + normal_e[n]) * scale, partitionable threefry bits:
// bits[n] = lane0 ^ lane1 of enc(key; hi=0, lo=n)
__global__ __launch_bounds__(256) void gen_kernel(
    float* __restrict__ out, uint32_t kh0, uint32_t kh1, uint32_t ke0,
    uint32_t ke1, float scale, int n4) {
  int t = blockIdx.x * 256 + threadIdx.x;
  if (t >= n4) return;
  uint32_t base = (uint32_t)t * 4u;
  float v[4];
#pragma unroll
  for (int j = 0; j < 4; ++j) {
    uint32_t n = base + (uint32_t)j;
    uint32_t h0, h1, e0, e1;
    threefry2x32(kh0, kh1, 0u, n, h0, h1);
    threefry2x32(ke0, ke1, 0u, n, e0, e1);
    v[j] = (bits_to_normal(h0 ^ h1) + bits_to_normal(e0 ^ e1)) * scale;
  }
  float4 o;
  o.x = v[0]; o.y = v[1]; o.z = v[2]; o.w = v[3];
  reinterpret_cast<float4*>(out)[t] = o;
}

// fallback: all branches False -> out = (h + e) * 0.7^64
__global__ __launch_bounds__(256) void blend_kernel(
    const float4* __restrict__ a, const float4* __restrict__ b,
    float4* __restrict__ out, float s, int n4) {
  int t = blockIdx.x * 256 + threadIdx.x;
  if (t >= n4) return;
  float4 x = a[t], y = b[t];
  float4 o;
  o.x = (x.x + y.x) * s;
  o.y = (x.y + y.y) * s;
  o.z = (x.z + y.z) * s;
  o.w = (x.w + y.w) * s;
  out[t] = o;
}

extern "C" void kernel_launch(void* const* d_in, const int* in_sizes, int n_in,
                              void* d_out, int out_size, void* d_ws,
                              size_t ws_size, hipStream_t stream) {
  const float* h_in = (const float*)d_in[0];
  const float* e_in = (const float*)d_in[1];
  float* out = (float*)d_out;

  // -------------------------------------------------------------------------
  // Host-side deterministic trace of the 64 scan steps (pure CPU arithmetic,
  // identical every call — graph-capture safe).
  // base key = jax.random.key(42) -> (0, 42)
  // partitionable split: key_i = enc(key; 0, i) as (lane0, lane1)
  // -------------------------------------------------------------------------
  const uint32_t bk0 = 0u, bk1 = 42u;
  int last_true = -1;
  uint32_t kh0 = 0, kh1 = 0, ke0 = 0, ke1 = 0;
  for (uint32_t i = 0; i < 64; ++i) {
    uint32_t ki0, ki1;
    threefry2x32(bk0, bk1, 0u, i, ki0, ki1);
    // split(key_i, 3) -> kb (counter 0), kh (counter 1), ke (counter 2)
    uint32_t kb0, kb1, tkh0, tkh1, tke0, tke1;
    threefry2x32(ki0, ki1, 0u, 0u, kb0, kb1);
    threefry2x32(ki0, ki1, 0u, 1u, tkh0, tkh1);
    threefry2x32(ki0, ki1, 0u, 2u, tke0, tke1);
    // uniform(kb, ()) : bits = lane0 ^ lane1 of enc(kb; 0, 0)
    uint32_t ub0, ub1;
    threefry2x32(kb0, kb1, 0u, 0u, ub0, ub1);
    uint32_t bits = ub0 ^ ub1;
    uint32_t fb = (bits >> 9) | 0x3f800000u;
    float f;
    memcpy(&f, &fb, 4);
    f -= 1.0f;  // uniform in [0,1)
    if (f < 0.5f) {  // RAND_RATIO
      last_true = (int)i;
      kh0 = tkh0; kh1 = tkh1; ke0 = tke0; ke1 = tke1;
    }
  }

  const int n4 = out_size / 4;
  const int grid = (n4 + 255) / 256;

  if (last_true >= 0) {
    const int c = 63 - last_true;  // number of *0.7 steps after last redraw
    float scale = 1.0f;
    for (int j = 0; j < c; ++j) scale *= 0.7f;
    gen_kernel<<<grid, 256, 0, stream>>>(out, kh0, kh1, ke0, ke1, scale, n4);
  } else {
    float scale = 1.0f;
    for (int j = 0; j < 64; ++j) scale *= 0.7f;
    blend_kernel<<<grid, 256, 0, stream>>>(
        (const float4*)h_in, (const float4*)e_in, (float4*)out, scale, n4);
  }
}

// Round 2
// 280.159 us; speedup vs baseline: 1.0071x; 1.0071x over previous
//
#include <hip/hip_runtime.h>
#include <stdint.h>
#include <string.h>

// ---------------------------------------------------------------------------
// JAX threefry2x32 (20 rounds), exact reproduction of
// jax/_src/prng.py::_threefry2x32 (partitionable layout).
// Host copy used for the 64-step branch trace.
// ---------------------------------------------------------------------------
static inline uint32_t h_rotl32(uint32_t x, uint32_t r) {
  return (x << r) | (x >> (32u - r));
}

static void h_threefry2x32(uint32_t k0, uint32_t k1, uint32_t x0, uint32_t x1,
                           uint32_t& o0, uint32_t& o1) {
  const uint32_t ks2 = k0 ^ k1 ^ 0x1BD11BDAu;
  x0 += k0; x1 += k1;
  x0 += x1; x1 = h_rotl32(x1, 13); x1 ^= x0;
  x0 += x1; x1 = h_rotl32(x1, 15); x1 ^= x0;
  x0 += x1; x1 = h_rotl32(x1, 26); x1 ^= x0;
  x0 += x1; x1 = h_rotl32(x1,  6); x1 ^= x0;
  x0 += k1; x1 += ks2 + 1u;
  x0 += x1; x1 = h_rotl32(x1, 17); x1 ^= x0;
  x0 += x1; x1 = h_rotl32(x1, 29); x1 ^= x0;
  x0 += x1; x1 = h_rotl32(x1, 16); x1 ^= x0;
  x0 += x1; x1 = h_rotl32(x1, 24); x1 ^= x0;
  x0 += ks2; x1 += k0 + 2u;
  x0 += x1; x1 = h_rotl32(x1, 13); x1 ^= x0;
  x0 += x1; x1 = h_rotl32(x1, 15); x1 ^= x0;
  x0 += x1; x1 = h_rotl32(x1, 26); x1 ^= x0;
  x0 += x1; x1 = h_rotl32(x1,  6); x1 ^= x0;
  x0 += k0; x1 += k1 + 3u;
  x0 += x1; x1 = h_rotl32(x1, 17); x1 ^= x0;
  x0 += x1; x1 = h_rotl32(x1, 29); x1 ^= x0;
  x0 += x1; x1 = h_rotl32(x1, 16); x1 ^= x0;
  x0 += x1; x1 = h_rotl32(x1, 24); x1 ^= x0;
  x0 += k1; x1 += ks2 + 4u;
  x0 += x1; x1 = h_rotl32(x1, 13); x1 ^= x0;
  x0 += x1; x1 = h_rotl32(x1, 15); x1 ^= x0;
  x0 += x1; x1 = h_rotl32(x1, 26); x1 ^= x0;
  x0 += x1; x1 = h_rotl32(x1,  6); x1 ^= x0;
  o0 = x0 + ks2;
  o1 = x1 + k0 + 5u;
}

// ---------------------------------------------------------------------------
// Device: dual interleaved threefry (h-key and e-key ciphers on the same
// counter n), rotates forced to single v_alignbit_b32, fold o0^o1.
// Two independent dependency chains -> ILP for the scheduler.
// ---------------------------------------------------------------------------
#define TF_R(x0, x1, r)                                   \
  x0 += x1;                                               \
  x1 = __builtin_amdgcn_alignbit(x1, x1, 32u - (r));      \
  x1 ^= x0;

#define TF_G(r1, r2, r3, r4)                              \
  TF_R(a0, a1, r1) TF_R(b0, b1, r1)                       \
  TF_R(a0, a1, r2) TF_R(b0, b1, r2)                       \
  TF_R(a0, a1, r3) TF_R(b0, b1, r3)                       \
  TF_R(a0, a1, r4) TF_R(b0, b1, r4)

__device__ inline void dual_tf_fold(uint32_t hk0, uint32_t hk1, uint32_t hks,
                                    uint32_t ek0, uint32_t ek1, uint32_t eks,
                                    uint32_t n, uint32_t& oh, uint32_t& oe) {
  uint32_t a0 = hk0, a1 = n + hk1;   // init key injection (x0=0, x1=n)
  uint32_t b0 = ek0, b1 = n + ek1;
  TF_G(13, 15, 26, 6)
  a0 += hk1; a1 += hks + 1u;  b0 += ek1; b1 += eks + 1u;
  TF_G(17, 29, 16, 24)
  a0 += hks; a1 += hk0 + 2u;  b0 += eks; b1 += ek0 + 2u;
  TF_G(13, 15, 26, 6)
  a0 += hk0; a1 += hk1 + 3u;  b0 += ek0; b1 += ek1 + 3u;
  TF_G(17, 29, 16, 24)
  a0 += hk1; a1 += hks + 4u;  b0 += ek1; b1 += eks + 4u;
  TF_G(13, 15, 26, 6)
  oh = (a0 + hks) ^ (a1 + hk0 + 5u);
  oe = (b0 + eks) ^ (b1 + ek0 + 5u);
}

// bits -> p*u where normal = sqrt(2)*p*u (Giles erfinv poly, XLA-compatible).
// Caller applies the folded sqrt(2)*scale constant once per output element.
__device__ inline float bits_to_pu(uint32_t bits) {
  const float LO = -0.99999994f;  // nextafterf(-1, 0) — matches jax uniform lo
  float f = __uint_as_float((bits >> 9) | 0x3f800000u) - 1.0f;  // exact
  float u = fmaxf(LO, __builtin_fmaf(f, 2.0f, LO));
  float t = u * u;
  float w = -__logf(1.0f - t);
  float p;
  if (w < 5.0f) {
    float ww = w - 2.5f;
    p = 2.81022636e-08f;
    p = __builtin_fmaf(p, ww, 3.43273939e-07f);
    p = __builtin_fmaf(p, ww, -3.5233877e-06f);
    p = __builtin_fmaf(p, ww, -4.39150654e-06f);
    p = __builtin_fmaf(p, ww, 0.00021858087f);
    p = __builtin_fmaf(p, ww, -0.00125372503f);
    p = __builtin_fmaf(p, ww, -0.00417768164f);
    p = __builtin_fmaf(p, ww, 0.246640727f);
    p = __builtin_fmaf(p, ww, 1.50140941f);
  } else {
    float ww = sqrtf(w) - 3.0f;
    p = -0.000200214257f;
    p = __builtin_fmaf(p, ww, 0.000100950558f);
    p = __builtin_fmaf(p, ww, 0.00134934322f);
    p = __builtin_fmaf(p, ww, -0.00367342844f);
    p = __builtin_fmaf(p, ww, 0.00573950773f);
    p = __builtin_fmaf(p, ww, -0.0076224613f);
    p = __builtin_fmaf(p, ww, 0.00943887047f);
    p = __builtin_fmaf(p, ww, 1.00167406f);
    p = __builtin_fmaf(p, ww, 2.83297682f);
  }
  return p * u;
}

// out[n] = (normal_h[n] + normal_e[n]) * scale
//        = FS * (pu_h + pu_e),  FS = sqrt(2)*scale  (host-folded)
__global__ __launch_bounds__(256) void gen_kernel(
    float* __restrict__ out, uint32_t kh0, uint32_t kh1, uint32_t khs,
    uint32_t ke0, uint32_t ke1, uint32_t kes, float FS, int n4) {
  int t = blockIdx.x * 256 + threadIdx.x;
  if (t >= n4) return;
  uint32_t base = (uint32_t)t * 4u;
  float4 o;
  float v[4];
#pragma unroll
  for (int j = 0; j < 4; ++j) {
    uint32_t oh, oe;
    dual_tf_fold(kh0, kh1, khs, ke0, ke1, kes, base + (uint32_t)j, oh, oe);
    v[j] = FS * (bits_to_pu(oh) + bits_to_pu(oe));
  }
  o.x = v[0]; o.y = v[1]; o.z = v[2]; o.w = v[3];
  reinterpret_cast<float4*>(out)[t] = o;
}

// fallback: all branches False -> out = (h + e) * 0.7^64
__global__ __launch_bounds__(256) void blend_kernel(
    const float4* __restrict__ a, const float4* __restrict__ b,
    float4* __restrict__ out, float s, int n4) {
  int t = blockIdx.x * 256 + threadIdx.x;
  if (t >= n4) return;
  float4 x = a[t], y = b[t];
  float4 o;
  o.x = (x.x + y.x) * s;
  o.y = (x.y + y.y) * s;
  o.z = (x.z + y.z) * s;
  o.w = (x.w + y.w) * s;
  out[t] = o;
}

extern "C" void kernel_launch(void* const* d_in, const int* in_sizes, int n_in,
                              void* d_out, int out_size, void* d_ws,
                              size_t ws_size, hipStream_t stream) {
  const float* h_in = (const float*)d_in[0];
  const float* e_in = (const float*)d_in[1];
  float* out = (float*)d_out;

  // Host-side deterministic trace of the 64 scan steps (identical every call).
  // base key = jax.random.key(42) -> (0, 42); partitionable split:
  // key_i = enc(key; 0, i); split(key_i,3) -> counters 0,1,2;
  // uniform bits = lane0 ^ lane1 of enc(kb; 0, 0).
  const uint32_t bk0 = 0u, bk1 = 42u;
  int last_true = -1;
  uint32_t kh0 = 0, kh1 = 0, ke0 = 0, ke1 = 0;
  for (uint32_t i = 0; i < 64; ++i) {
    uint32_t ki0, ki1;
    h_threefry2x32(bk0, bk1, 0u, i, ki0, ki1);
    uint32_t kb0, kb1, tkh0, tkh1, tke0, tke1;
    h_threefry2x32(ki0, ki1, 0u, 0u, kb0, kb1);
    h_threefry2x32(ki0, ki1, 0u, 1u, tkh0, tkh1);
    h_threefry2x32(ki0, ki1, 0u, 2u, tke0, tke1);
    uint32_t ub0, ub1;
    h_threefry2x32(kb0, kb1, 0u, 0u, ub0, ub1);
    uint32_t bits = ub0 ^ ub1;
    uint32_t fb = (bits >> 9) | 0x3f800000u;
    float f;
    memcpy(&f, &fb, 4);
    f -= 1.0f;  // uniform in [0,1)
    if (f < 0.5f) {  // RAND_RATIO
      last_true = (int)i;
      kh0 = tkh0; kh1 = tkh1; ke0 = tke0; ke1 = tke1;
    }
  }

  const int n4 = out_size / 4;
  const int grid = (n4 + 255) / 256;

  if (last_true >= 0) {
    const int c = 63 - last_true;
    float scale = 1.0f;
    for (int j = 0; j < c; ++j) scale *= 0.7f;
    const float FS = 1.41421356f * scale;
    const uint32_t khs = kh0 ^ kh1 ^ 0x1BD11BDAu;
    const uint32_t kes = ke0 ^ ke1 ^ 0x1BD11BDAu;
    gen_kernel<<<grid, 256, 0, stream>>>(out, kh0, kh1, khs, ke0, ke1, kes, FS,
                                         n4);
  } else {
    float scale = 1.0f;
    for (int j = 0; j < 64; ++j) scale *= 0.7f;
    blend_kernel<<<grid, 256, 0, stream>>>(
        (const float4*)h_in, (const float4*)e_in, (float4*)out, scale, n4);
  }
}